// Round 13
// baseline (673.397 us; speedup 1.0000x reference)
//
#include <hip/hip_runtime.h>
#include <hip/hip_bf16.h>

#define TC    2049
#define DI    512
#define NS    128
#define XPN   288   // DT_RANK + 2*N_STATE = 32 + 256

typedef short bfx8 __attribute__((ext_vector_type(8)));
typedef float f32x4 __attribute__((ext_vector_type(4)));

__device__ __forceinline__ float us2f(unsigned short u) {
    union { unsigned int i; float f; } v; v.i = ((unsigned int)u) << 16; return v.f;
}
__device__ __forceinline__ unsigned short f2bf(float f) {
    unsigned int u = __float_as_uint(f);
    u = (u + 0x7FFF + ((u >> 16) & 1)) >> 16;   // round-to-nearest-even
    return (unsigned short)u;
}
__device__ __forceinline__ float sigm(float x) { return 1.f / (1.f + __expf(-x)); }

#define L2E 1.4426950408889634f

// raw v_exp_f32 (args are always <= 0 here; native flush behavior is correct)
__device__ __forceinline__ float fexp2(float x) {
#if __has_builtin(__builtin_amdgcn_exp2f)
    return __builtin_amdgcn_exp2f(x);
#else
    return __expf(x * 0.6931471805599453f);
#endif
}

// ---------------- dtype sniffing: bf16 inputs (flag=0) vs f32 inputs (flag=1) -----
__global__ void detect_kernel(const unsigned short* __restrict__ x, int* __restrict__ flag) {
    __shared__ int cnt;
    int tid = threadIdx.x;
    if (tid == 0) cnt = 0;
    __syncthreads();
    unsigned short u = x[tid];
    int e = (u >> 7) & 0xFF;
    int insane = (u != 0 && (e < 97 || e > 157)) ? 1 : 0;
    atomicAdd(&cnt, insane);
    __syncthreads();
    if (tid == 0) *flag = (cnt >= 64) ? 1 : 0;
}

// ---------------- widen inputs to f32 in workspace (23 plain entries) ----------------
struct WD { const void* src; float* dst; int n; };
struct WDT { WD e[23]; };
__global__ __launch_bounds__(256) void widen_all_kernel(WDT tab, const int* __restrict__ flag) {
    WD d = tab.e[blockIdx.y];
    const int f = *flag;
    const int stride = gridDim.x * 256;
    int i = blockIdx.x * 256 + threadIdx.x;
    if (f) {
        const float* s = (const float*)d.src;
        for (; i < d.n; i += stride) d.dst[i] = s[i];
    } else {
        const unsigned short* s = (const unsigned short*)d.src;
        for (; i < d.n; i += stride) d.dst[i] = us2f(s[i]);
    }
}

// ---------------- widen + column-permute the xproj weights -----------------------
__global__ __launch_bounds__(256) void widen_permute_xproj_kernel(
    const void* __restrict__ src, float* __restrict__ dst, const int* __restrict__ flag)
{
    int i = blockIdx.x * 256 + threadIdx.x;   // 512*288 = 147456
    if (i >= 147456) return;
    int k = i / 288, c = i - k * 288;
    int s;
    if (c < 32) s = c;
    else if (c < 160) { int q = c - 32;  s = 32  + (q >> 2) + 32 * (q & 3); }
    else             { int q = c - 160; s = 160 + (q >> 2) + 32 * (q & 3); }
    int si = k * 288 + s;
    float v = (*flag) ? ((const float*)src)[si] : us2f(((const unsigned short*)src)[si]);
    dst[i] = v;
}

// ---------------- bf16-MFMA GEMM (f32 in/out, bf16 matrix cores) ------------------
__global__ __launch_bounds__(256) void gemm_mfma_kernel(
    const float* __restrict__ A, int lda, long long sA,
    const float* __restrict__ W, int N,
    const float* __restrict__ bias,
    float* __restrict__ C, int ldc, long long sC,
    int M, int K, int act)
{
    A += (size_t)blockIdx.z * sA;
    C += (size_t)blockIdx.z * sC;
    __shared__ __align__(16) unsigned short As[64][40];   // [m][k] bf16
    __shared__ __align__(16) unsigned short Bs[64][40];   // [n][k] bf16 (transposed)
    const int tid = threadIdx.x;
    const int wave = tid >> 6, lane = tid & 63;
    const int bm = blockIdx.x * 64, bn = blockIdx.y * 64;
    const int col = lane & 15, quad = lane >> 4;

    f32x4 acc[4] = {{0.f,0.f,0.f,0.f},{0.f,0.f,0.f,0.f},{0.f,0.f,0.f,0.f},{0.f,0.f,0.f,0.f}};

    const int ar = tid >> 2, ak = (tid & 3) << 3;
    const int kr = tid >> 3, nb = (tid & 7) << 3;

    for (int kt = 0; kt < K; kt += 32) {
        float va[8];
        int gm = bm + ar;
        if (gm < M) {
            const float* ap = A + (size_t)gm * lda + kt + ak;
            float4 v0 = *(const float4*)ap;
            float4 v1 = *(const float4*)(ap + 4);
            va[0]=v0.x; va[1]=v0.y; va[2]=v0.z; va[3]=v0.w;
            va[4]=v1.x; va[5]=v1.y; va[6]=v1.z; va[7]=v1.w;
        } else {
#pragma unroll
            for (int j = 0; j < 8; ++j) va[j] = 0.f;
        }
        float vb[8];
        int gn0 = bn + nb;
        const float* wp = W + (size_t)(kt + kr) * N + gn0;
        if (gn0 + 7 < N) {
            float4 w0 = *(const float4*)wp;
            float4 w1 = *(const float4*)(wp + 4);
            vb[0]=w0.x; vb[1]=w0.y; vb[2]=w0.z; vb[3]=w0.w;
            vb[4]=w1.x; vb[5]=w1.y; vb[6]=w1.z; vb[7]=w1.w;
        } else {
#pragma unroll
            for (int j = 0; j < 8; ++j) vb[j] = (gn0 + j < N) ? wp[j] : 0.f;
        }
        __syncthreads();
        bfx8 apk;
#pragma unroll
        for (int j = 0; j < 8; ++j) apk[j] = (short)f2bf(va[j]);
        *(bfx8*)&As[ar][ak] = apk;
#pragma unroll
        for (int j = 0; j < 8; ++j) Bs[nb + j][kr] = f2bf(vb[j]);
        __syncthreads();
        bfx8 af = *(const bfx8*)&As[wave * 16 + col][quad << 3];
#pragma unroll
        for (int ct = 0; ct < 4; ++ct) {
            bfx8 bf = *(const bfx8*)&Bs[ct * 16 + col][quad << 3];
            acc[ct] = __builtin_amdgcn_mfma_f32_16x16x32_bf16(af, bf, acc[ct], 0, 0, 0);
        }
    }
#pragma unroll
    for (int ct = 0; ct < 4; ++ct) {
        int gn = bn + ct * 16 + col;
        if (gn >= N) continue;
        float bv = bias ? bias[gn] : 0.f;
#pragma unroll
        for (int r = 0; r < 4; ++r) {
            int gm = bm + wave * 16 + quad * 4 + r;
            if (gm < M) {
                float v = acc[ct][r] + bv;
                if (act == 1) v = fmaxf(v, 0.f);
                C[(size_t)gm * ldc + gn] = v;
            }
        }
    }
}

// ---------------- causal depthwise conv (K=4) + silu, batched 2 dirs ----------------
__global__ __launch_bounds__(256) void conv_silu_kernel(
    const float* __restrict__ xzbase, int ld, long long bstride,
    const float* __restrict__ conv_w, const float* __restrict__ conv_b,
    float* __restrict__ xs, int T, int rev_mode)
{
    int idx = blockIdx.x * 256 + threadIdx.x;
    if (idx >= 2 * T * DI) return;
    int half = idx / (T * DI);
    int rem = idx - half * T * DI;
    int t = rem >> 9, d = rem & 511;
    const float* xzp = xzbase + (rev_mode ? 0 : (size_t)half * bstride);
    int rev = rev_mode ? half : 0;
    float acc = conv_b[d];
#pragma unroll
    for (int k = 0; k < 4; ++k) {
        int tt = t - 3 + k;
        if (tt >= 0) {
            int g = rev ? (T - 1 - tt) : tt;
            acc += conv_w[d * 4 + k] * xzp[(size_t)g * ld + d];
        }
    }
    xs[idx] = acc * sigm(acc);
}

// ---------------- dt projection (K=32) + softplus ----------------
__global__ __launch_bounds__(256) void dt_kernel(
    const float* __restrict__ xdbl, const float* __restrict__ dt_w,
    const float* __restrict__ dt_b, float* __restrict__ dtout, int T)
{
    int idx = blockIdx.x * 256 + threadIdx.x;
    if (idx >= 2 * T * DI) return;
    int half = idx / (T * DI);
    int rem = idx - half * T * DI;
    int t = rem >> 9, j = rem & 511;
    const float* a = xdbl + (size_t)half * T * XPN + (size_t)t * XPN;
    float acc = dt_b[j];
#pragma unroll
    for (int k = 0; k < 32; ++k) acc += a[k] * dt_w[k * DI + j];
    dtout[idx] = (acc > 20.f) ? acc : log1pf(__expf(acc));
}

// ---------------- chunked scan pass 1 (2 d's/wave, 4 waves/block, unroll x2) --------
__global__ __launch_bounds__(256) void scan_part1_kernel(
    const float* __restrict__ dt, const float* __restrict__ xdbl,
    const float* __restrict__ xs, const float* __restrict__ A_log,
    float* __restrict__ P, float* __restrict__ H, int T, int NC, int LC)
{
    int b = blockIdx.x * 4 + (threadIdx.x >> 6);
    int c = b % NC;
    int dp = b / NC;
    int hd0 = dp * 2;
    int half = hd0 >> 9;
    int lane = threadIdx.x & 63;
    int g = lane >> 5, l = lane & 31;
    int hd = hd0 + g;
    int d = hd & 511;
    const float a0 = -__expf(A_log[d * NS + l])      * L2E;
    const float a1 = -__expf(A_log[d * NS + 32 + l]) * L2E;
    const float a2 = -__expf(A_log[d * NS + 64 + l]) * L2E;
    const float a3 = -__expf(A_log[d * NS + 96 + l]) * L2E;
    int t0 = c * LC, t1 = min(T, t0 + LC);
    const float* dtp = dt + (size_t)half * T * DI + (size_t)t0 * DI + d;
    const float* xsp = xs + (size_t)half * T * DI + (size_t)t0 * DI + d;
    const float* row = xdbl + (size_t)half * T * XPN + (size_t)t0 * XPN + 32 + 4 * l;
    float P0 = 1.f, P1 = 1.f, P2 = 1.f, P3 = 1.f;
    float h0 = 0.f, h1 = 0.f, h2 = 0.f, h3 = 0.f;
    int t = t0;
    for (; t + 2 <= t1; t += 2) {
        float dva = dtp[0],  xva = xsp[0];
        float dvb = dtp[DI], xvb = xsp[DI];
        float4 Ba = *(const float4*)row;
        float4 Bb = *(const float4*)(row + XPN);
        float e0a = fexp2(dva * a0), e1a = fexp2(dva * a1);
        float e2a = fexp2(dva * a2), e3a = fexp2(dva * a3);
        float e0b = fexp2(dvb * a0), e1b = fexp2(dvb * a1);
        float e2b = fexp2(dvb * a2), e3b = fexp2(dvb * a3);
        float ua = dva * xva, ub = dvb * xvb;
        h0 = h0 * e0a + ua * Ba.x;  h1 = h1 * e1a + ua * Ba.y;
        h2 = h2 * e2a + ua * Ba.z;  h3 = h3 * e3a + ua * Ba.w;
        h0 = h0 * e0b + ub * Bb.x;  h1 = h1 * e1b + ub * Bb.y;
        h2 = h2 * e2b + ub * Bb.z;  h3 = h3 * e3b + ub * Bb.w;
        P0 *= e0a * e0b; P1 *= e1a * e1b; P2 *= e2a * e2b; P3 *= e3a * e3b;
        dtp += 2 * DI; xsp += 2 * DI; row += 2 * XPN;
    }
    for (; t < t1; ++t) {
        float dv = *dtp, xv = *xsp;
        float4 Bv = *(const float4*)row;
        float e0 = fexp2(dv * a0), e1 = fexp2(dv * a1);
        float e2 = fexp2(dv * a2), e3 = fexp2(dv * a3);
        float u = dv * xv;
        h0 = h0 * e0 + u * Bv.x;  h1 = h1 * e1 + u * Bv.y;
        h2 = h2 * e2 + u * Bv.z;  h3 = h3 * e3 + u * Bv.w;
        P0 *= e0; P1 *= e1; P2 *= e2; P3 *= e3;
        dtp += DI; xsp += DI; row += XPN;
    }
    size_t base = ((size_t)hd * NC + c) * 128 + l;
    P[base] = P0; P[base + 32] = P1; P[base + 64] = P2; P[base + 96] = P3;
    H[base] = h0; H[base + 32] = h1; H[base + 64] = h2; H[base + 96] = h3;
}

// ---------------- chunked scan pass 2: serial combine across chunks ----------------
__global__ __launch_bounds__(128) void scan_combine_kernel(
    float* __restrict__ P, const float* __restrict__ H,
    float* __restrict__ Hfinal, int NC)
{
    int hd = blockIdx.x;
    int n = threadIdx.x;
    size_t base = (size_t)hd * NC * 128 + n;
    float h = 0.f;
    for (int c = 0; c < NC; ++c) {
        size_t off = base + (size_t)c * 128;
        float p = P[off];
        float hh = H[off];
        P[off] = h;                // h_start for chunk c (exclusive prefix)
        h = p * h + hh;
    }
    if (Hfinal) Hfinal[(size_t)hd * 128 + n] = h;
}

// ---------------- chunked scan pass 3: replay + emit GATED y (no unroll) ------------
__global__ __launch_bounds__(256) void scan_emit_kernel(
    const float* __restrict__ dt, const float* __restrict__ xdbl,
    const float* __restrict__ xs, const float* __restrict__ xz,
    const float* __restrict__ A_log, const float* __restrict__ Hstart,
    const float* __restrict__ Dp,
    float* __restrict__ y, int T, int NC, int LC)
{
    int b = blockIdx.x * 4 + (threadIdx.x >> 6);
    int c = b % NC;
    int dp = b / NC;
    int hd0 = dp * 2;
    int half = hd0 >> 9;
    int lane = threadIdx.x & 63;
    int g = lane >> 5, l = lane & 31;
    int hd = hd0 + g;
    int d = hd & 511;
    const float a0 = -__expf(A_log[d * NS + l])      * L2E;
    const float a1 = -__expf(A_log[d * NS + 32 + l]) * L2E;
    const float a2 = -__expf(A_log[d * NS + 64 + l]) * L2E;
    const float a3 = -__expf(A_log[d * NS + 96 + l]) * L2E;
    const float Dv = Dp[d];
    size_t base = ((size_t)hd * NC + c) * 128 + l;
    float h0 = Hstart[base];
    float h1 = Hstart[base + 32];
    float h2 = Hstart[base + 64];
    float h3 = Hstart[base + 96];
    int t0 = c * LC, t1 = min(T, t0 + LC);
    const float* dtp = dt + (size_t)half * T * DI + (size_t)t0 * DI + d;
    const float* xsp = xs + (size_t)half * T * DI + (size_t)t0 * DI + d;
    const float* row = xdbl + (size_t)half * T * XPN + (size_t)t0 * XPN + 4 * l;
    // flip-aware z pointer: tg0 = half ? T-1-t0 : t0 ; step = half ? -1024 : +1024
    const float* zp = xz + 512 + d + (size_t)(half ? (T - 1 - t0) : t0) * 1024;
    const int zstep = half ? -1024 : 1024;
    float* yp = y + (size_t)half * T * DI + (size_t)t0 * DI + d;
    for (int t = t0; t < t1; ++t) {
        float dv = *dtp, xv = *xsp;
        float4 Bv = *(const float4*)(row + 32);
        float4 Cv = *(const float4*)(row + 160);
        float e0 = fexp2(dv * a0), e1 = fexp2(dv * a1);
        float e2 = fexp2(dv * a2), e3 = fexp2(dv * a3);
        float u = dv * xv;
        h0 = h0 * e0 + u * Bv.x;  h1 = h1 * e1 + u * Bv.y;
        h2 = h2 * e2 + u * Bv.z;  h3 = h3 * e3 + u * Bv.w;
        float p = h0 * Cv.x + h1 * Cv.y + h2 * Cv.z + h3 * Cv.w;
        p += __shfl_xor(p, 1, 64);
        p += __shfl_xor(p, 2, 64);
        p += __shfl_xor(p, 4, 64);
        p += __shfl_xor(p, 8, 64);
        p += __shfl_xor(p, 16, 64);
        if (l == 0) {
            float z = *zp;
            *yp = (p + xv * Dv) * (z * sigm(z));
        }
        dtp += DI; xsp += DI; row += XPN; yp += DI; zp += zstep;
    }
}

// ---------------- cross: last-step readout (permuted C layout) ----------------
__global__ __launch_bounds__(64) void cross_readout_kernel(
    const float* __restrict__ Hfinal, const float* __restrict__ xdbl,
    const float* __restrict__ xs, const float* __restrict__ xz,
    const float* __restrict__ Dp, float* __restrict__ ylast, int T)
{
    int hd = blockIdx.x;
    int half = hd >> 9, d = hd & 511;
    int lane = threadIdx.x;
    xdbl += (size_t)half * T * XPN;
    xs   += (size_t)half * T * DI;
    xz   += (size_t)half * T * 1024;
    float h0 = Hfinal[(size_t)hd * 128 + lane];          // state n = lane
    float h1 = Hfinal[(size_t)hd * 128 + 64 + lane];     // state n = 64+lane
    const float* xl = xdbl + (size_t)(T - 1) * XPN;
    int lb = lane & 31, j = lane >> 5;
    float C0 = xl[160 + 4 * lb + j];        // permuted col of state n=lane
    float C1 = xl[160 + 4 * lb + 2 + j];    // permuted col of state n=64+lane
    float p = h0 * C0 + h1 * C1;
#pragma unroll
    for (int off = 32; off > 0; off >>= 1) p += __shfl_down(p, off, 64);
    if (lane == 0) {
        float xlast = xs[(size_t)(T - 1) * DI + d];
        float zl = xz[(size_t)(T - 1) * 1024 + 512 + d];
        ylast[half * DI + d] = (p + xlast * Dp[d]) * (zl * sigm(zl));
    }
}

// ---------------- row softmax + scatter into both cross sequences ----------------
__global__ __launch_bounds__(256) void softmax_scatter_kernel(
    const float* __restrict__ yo, float* __restrict__ seq, int T)
{
    __shared__ float sm[4];
    const int t = blockIdx.x, half = blockIdx.y, tid = threadIdx.x;
    const float* row = yo + (size_t)half * T * DI + (size_t)t * DI;
    float v0 = row[tid], v1 = row[tid + 256];
    float m = fmaxf(v0, v1);
#pragma unroll
    for (int o = 32; o > 0; o >>= 1) m = fmaxf(m, __shfl_xor(m, o, 64));
    if ((tid & 63) == 0) sm[tid >> 6] = m;
    __syncthreads();
    m = fmaxf(fmaxf(sm[0], sm[1]), fmaxf(sm[2], sm[3]));
    __syncthreads();
    float e0 = __expf(v0 - m), e1 = __expf(v1 - m);
    float s = e0 + e1;
#pragma unroll
    for (int o = 32; o > 0; o >>= 1) s += __shfl_xor(s, o, 64);
    if ((tid & 63) == 0) sm[tid >> 6] = s;
    __syncthreads();
    s = sm[0] + sm[1] + sm[2] + sm[3];
    float inv = 1.f / s;
    e0 *= inv; e1 *= inv;
    float* seq_fi = seq;
    float* seq_if = seq + (size_t)TC * 1024;
    if (half == 0) {
        float* d1 = seq_fi + (size_t)t * 1024;
        float* d2 = seq_if + (size_t)t * 1024 + 512;
        d1[tid] = e0; d1[tid + 256] = e1;
        d2[tid] = e0; d2[tid + 256] = e1;
    } else {
        int tg = T - 1 - t;
        float* d1 = seq_fi + (size_t)tg * 1024 + 512;
        float* d2 = seq_if + (size_t)tg * 1024;
        d1[tid] = e0; d1[tid + 256] = e1;
        d2[tid] = e0; d2[tid + 256] = e1;
    }
}

// ---------------- cls-token rows of the two sequences ----------------
__global__ __launch_bounds__(256) void cls_rows_kernel(
    const float* __restrict__ cls1, const float* __restrict__ cls2,
    float* __restrict__ seq)
{
    int i = blockIdx.x * 256 + threadIdx.x;   // 0..2047
    if (i < 1024)
        seq[(size_t)(TC - 1) * 1024 + i] = cls1[i];
    else
        seq[(size_t)TC * 1024 + (size_t)(TC - 1) * 1024 + (i - 1024)] = cls2[i - 1024];
}

// ---------------- vec [512] @ out_w [512,512] -> [512] ----------------
__global__ __launch_bounds__(256) void vecmat_kernel(
    const float* __restrict__ ylast, const float* __restrict__ Wout,
    float* __restrict__ olast)
{
    int half = blockIdx.y;
    int j = blockIdx.x * 256 + threadIdx.x;
    const float* v = ylast + half * DI;
    float acc = 0.f;
    for (int k = 0; k < DI; ++k) acc += v[k] * Wout[k * DI + j];
    olast[half * DI + j] = acc;
}

// ---------------- final classifier -> f32 [2] ----------------
__global__ __launch_bounds__(256) void final_kernel(
    const float* __restrict__ ol, const float* __restrict__ cw,
    const float* __restrict__ cb, float* __restrict__ out)
{
    __shared__ float s0[4], s1[4];
    int tid = threadIdx.x;
    float a0 = 0.f, a1 = 0.f;
    for (int j = tid; j < 1024; j += 256) {
        float v = ol[j];
        a0 += v * cw[2 * j];
        a1 += v * cw[2 * j + 1];
    }
#pragma unroll
    for (int o = 32; o > 0; o >>= 1) { a0 += __shfl_xor(a0, o, 64); a1 += __shfl_xor(a1, o, 64); }
    if ((tid & 63) == 0) { s0[tid >> 6] = a0; s1[tid >> 6] = a1; }
    __syncthreads();
    if (tid == 0) {
        out[0] = s0[0] + s0[1] + s0[2] + s0[3] + cb[0];
        out[1] = s1[0] + s1[1] + s1[2] + s1[3] + cb[1];
    }
}

extern "C" void kernel_launch(void* const* d_in, const int* in_sizes, int n_in,
                              void* d_out, int out_size, void* d_ws, size_t ws_size,
                              hipStream_t stream)
{
    float* out = (float*)d_out;
    float* ws = (float*)d_ws;

    // ---- input-order resolution via in_sizes (dict vs signature order) ----
    static const int sig_map[25] = {0,1,2,3,4,23,24,5,6,7,8,9,10,11,12,13,
                                    14,15,16,17,18,19,20,21,22};
    int idx[25];
    bool dict_order = (n_in >= 7 && in_sizes[6] == 2);
    for (int i = 0; i < 25; ++i) idx[i] = dict_order ? i : sig_map[i];

    // ---- aliased workspace layout (f32 elements) ----
    const size_t A0 = 0;         // x(f32) -> dt_simple -> yo -> XSC          (2,098,176)
    const size_t B0 = 2098176;   // f -> XDC                                  (1,180,224)
    const size_t C0 = 3278400;   // XZS / XZC (XZC spans ..7,474,752)         (2,097,152)
    const size_t D0 = 5375552;   // XS                                        (2,097,152)
    const size_t E0 = 7472704;   // XDBL                                      (1,179,648)
    const size_t F0 = 8652352;   // y / YS                                    (2,097,152)
    const size_t G0 = 10749504;  // P_S | H_S  -> SEQ                         (4,196,352)
    const size_t YL0 = 14945856; // 1024
    const size_t OL0 = 14946880; // 1024
    const size_t DT_S = A0;
    const size_t P_S  = G0;
    const size_t H_S  = G0 + 2097152;
    const size_t DT_C = 7474752;
    const size_t P_C  = 9572928;
    const size_t H_C  = 11801152;
    const size_t HFIN = 14029376;
    size_t o = 14947904;
    const size_t P_FEATW = o; o += 524288;
    const size_t P_FEATB = o; o += 512;
    const size_t P_CLS1  = o; o += 1024;
    const size_t P_CLS2  = o; o += 1024;
    const size_t P_CLSW  = o; o += 2048;
    const size_t P_CLSB  = o; o += 4;
    const size_t P_MINW  = o; o += 524288;
    const size_t P_MCW   = o; o += 2048;
    const size_t P_MCB   = o; o += 512;
    const size_t P_MXP   = o; o += 147456;
    const size_t P_MDTW  = o; o += 16384;
    const size_t P_MDTB  = o; o += 512;
    const size_t P_MAL   = o; o += 65536;
    const size_t P_MD    = o; o += 512;
    const size_t P_MOW   = o; o += 262144;
    const size_t P_CINW  = o; o += 1048576;
    const size_t P_CCW   = o; o += 2048;
    const size_t P_CCB   = o; o += 512;
    const size_t P_CXP   = o; o += 147456;
    const size_t P_CDTW  = o; o += 16384;
    const size_t P_CDTB  = o; o += 512;
    const size_t P_CAL   = o; o += 65536;
    const size_t P_CD    = o; o += 512;
    const size_t P_COW   = o; o += 262144;
    const size_t OFF_FLAG = o;               // 1 int

    int* flagp = (int*)(ws + OFF_FLAG);

    // 0) detect input dtype
    detect_kernel<<<1, 256, 0, stream>>>((const unsigned short*)d_in[idx[0]], flagp);

    // 1) widen inputs (23 plain + 2 permuted xproj)
    WDT tab;
    const int lg[23]  = {0,1,2,3,4,5,6,7,8,9,11,12,13,14,15,16,17,18,20,21,22,23,24};
    const int nsl[25] = {2097152, 524288, 512, 1024, 1024, 2048, 2,
                         524288, 2048, 512, 147456, 16384, 512, 65536, 512, 262144,
                         1048576, 2048, 512, 147456, 16384, 512, 65536, 512, 262144};
    float* dstl[25] = {
        ws + A0, ws + P_FEATW, ws + P_FEATB, ws + P_CLS1, ws + P_CLS2,
        ws + P_CLSW, ws + P_CLSB,
        ws + P_MINW, ws + P_MCW, ws + P_MCB, nullptr, ws + P_MDTW, ws + P_MDTB,
        ws + P_MAL, ws + P_MD, ws + P_MOW,
        ws + P_CINW, ws + P_CCW, ws + P_CCB, nullptr, ws + P_CDTW, ws + P_CDTB,
        ws + P_CAL, ws + P_CD, ws + P_COW};
    for (int i = 0; i < 23; ++i) {
        int s = lg[i];
        tab.e[i].src = d_in[idx[s]];
        tab.e[i].dst = dstl[s];
        tab.e[i].n = nsl[s];
    }
    widen_all_kernel<<<dim3(128, 23), 256, 0, stream>>>(tab, flagp);
    widen_permute_xproj_kernel<<<576, 256, 0, stream>>>(d_in[idx[10]], ws + P_MXP, flagp);
    widen_permute_xproj_kernel<<<576, 256, 0, stream>>>(d_in[idx[19]], ws + P_CXP, flagp);

    // 2) f = relu(x @ feat_w + feat_b)        A -> B
    gemm_mfma_kernel<<<dim3(32, 8, 1), 256, 0, stream>>>(ws + A0, 1024, 0, ws + P_FEATW, 512,
                                                         ws + P_FEATB, ws + B0, 512, 0,
                                                         2048, 1024, 1);
    // 3) xz = f @ m_in_w                      B -> C
    gemm_mfma_kernel<<<dim3(32, 16, 1), 256, 0, stream>>>(ws + B0, 512, 0, ws + P_MINW, 1024,
                                                          nullptr, ws + C0, 1024, 0,
                                                          2048, 512, 0);
    // 4) conv+silu, both directions           C -> D
    conv_silu_kernel<<<8192, 256, 0, stream>>>(ws + C0, 1024, 0, ws + P_MCW, ws + P_MCB,
                                               ws + D0, 2048, 1);
    // 5) x_dbl = xs @ m_xproj_w (permuted)    D -> E
    gemm_mfma_kernel<<<dim3(32, 5, 2), 256, 0, stream>>>(ws + D0, 512, 2048LL * 512, ws + P_MXP,
                                                         288, nullptr, ws + E0, 288, 2048LL * 288,
                                                         2048, 512, 0);
    // 5b) dt = softplus(x_dbl[:, :32] @ dt_w + dt_b)   E -> DT_S (A)
    dt_kernel<<<8192, 256, 0, stream>>>(ws + E0, ws + P_MDTW, ws + P_MDTB, ws + DT_S, 2048);
    // 6) chunked scan: T=2048, 16 chunks x 128, 2 d's/wave, 4 waves/block
    scan_part1_kernel<<<2048, 256, 0, stream>>>(ws + DT_S, ws + E0, ws + D0, ws + P_MAL,
                                                ws + P_S, ws + H_S, 2048, 16, 128);
    scan_combine_kernel<<<1024, 128, 0, stream>>>(ws + P_S, ws + H_S, nullptr, 16);
    // emit with fused gating (reads xz from C, Dp)
    scan_emit_kernel<<<2048, 256, 0, stream>>>(ws + DT_S, ws + E0, ws + D0, ws + C0,
                                               ws + P_MAL, ws + P_S, ws + P_MD,
                                               ws + F0, 2048, 16, 128);
    // 7) yo = y @ m_out_w                     F -> A (yo)
    gemm_mfma_kernel<<<dim3(32, 8, 2), 256, 0, stream>>>(ws + F0, 512, 2048LL * 512, ws + P_MOW,
                                                         512, nullptr, ws + A0, 512, 2048LL * 512,
                                                         2048, 512, 0);
    // 8) cls-token rows into SEQ              P -> G
    cls_rows_kernel<<<8, 256, 0, stream>>>(ws + P_CLS1, ws + P_CLS2, ws + G0);
    // 9) softmax + scatter                    A -> G
    softmax_scatter_kernel<<<dim3(2048, 2), 256, 0, stream>>>(ws + A0, ws + G0, 2048);
    // 10) cross in-proj                       G -> C (XZC spans C,D,+head of E)
    gemm_mfma_kernel<<<dim3(33, 16, 2), 256, 0, stream>>>(ws + G0, 1024, 2049LL * 1024, ws + P_CINW,
                                                          1024, nullptr, ws + C0, 1024,
                                                          2049LL * 1024, 2049, 1024, 0);
    // 11) cross conv+silu                     C -> A (XSC)
    conv_silu_kernel<<<8196, 256, 0, stream>>>(ws + C0, 1024, 2049LL * 1024, ws + P_CCW,
                                               ws + P_CCB, ws + A0, 2049, 0);
    // 12) cross x_dbl (permuted)              A -> B (XDC)
    gemm_mfma_kernel<<<dim3(33, 5, 2), 256, 0, stream>>>(ws + A0, 512, 2049LL * 512, ws + P_CXP,
                                                         288, nullptr, ws + B0, 288, 2049LL * 288,
                                                         2049, 512, 0);
    // 12b) cross dt                           B -> DT_C
    dt_kernel<<<8196, 256, 0, stream>>>(ws + B0, ws + P_CDTW, ws + P_CDTB, ws + DT_C, 2049);
    // 13) cross chunked scan: T=2049, 17 chunks x 128
    scan_part1_kernel<<<2176, 256, 0, stream>>>(ws + DT_C, ws + B0, ws + A0, ws + P_CAL,
                                                ws + P_C, ws + H_C, 2049, 17, 128);
    scan_combine_kernel<<<1024, 128, 0, stream>>>(ws + P_C, ws + H_C, ws + HFIN, 17);
    cross_readout_kernel<<<1024, 64, 0, stream>>>(ws + HFIN, ws + B0, ws + A0, ws + C0,
                                                  ws + P_CD, ws + YL0, 2049);
    // 14) out-projection of last rows         YL -> OL
    vecmat_kernel<<<dim3(2, 2), 256, 0, stream>>>(ws + YL0, ws + P_COW, ws + OL0);
    // 15) classifier                          OL -> out (f32)
    final_kernel<<<1, 256, 0, stream>>>(ws + OL0, ws + P_CLSW, ws + P_CLSB, out);
}

// Round 14
// 657.024 us; speedup vs baseline: 1.0249x; 1.0249x over previous
//
#include <hip/hip_runtime.h>
#include <hip/hip_bf16.h>

#define TC    2049
#define DI    512
#define NS    128
#define XPN   288   // DT_RANK + 2*N_STATE = 32 + 256

typedef short bfx8 __attribute__((ext_vector_type(8)));
typedef float f32x4 __attribute__((ext_vector_type(4)));

__device__ __forceinline__ float us2f(unsigned short u) {
    union { unsigned int i; float f; } v; v.i = ((unsigned int)u) << 16; return v.f;
}
__device__ __forceinline__ unsigned short f2bf(float f) {
    unsigned int u = __float_as_uint(f);
    u = (u + 0x7FFF + ((u >> 16) & 1)) >> 16;   // round-to-nearest-even
    return (unsigned short)u;
}
__device__ __forceinline__ float sigm(float x) { return 1.f / (1.f + __expf(-x)); }

#define L2E 1.4426950408889634f

// raw v_exp_f32 (args are always <= 0 here; native flush behavior is correct)
__device__ __forceinline__ float fexp2(float x) {
#if __has_builtin(__builtin_amdgcn_exp2f)
    return __builtin_amdgcn_exp2f(x);
#else
    return __expf(x * 0.6931471805599453f);
#endif
}

// ---------------- dtype sniffing: bf16 inputs (flag=0) vs f32 inputs (flag=1) -----
__global__ void detect_kernel(const unsigned short* __restrict__ x, int* __restrict__ flag) {
    __shared__ int cnt;
    int tid = threadIdx.x;
    if (tid == 0) cnt = 0;
    __syncthreads();
    unsigned short u = x[tid];
    int e = (u >> 7) & 0xFF;
    int insane = (u != 0 && (e < 97 || e > 157)) ? 1 : 0;
    atomicAdd(&cnt, insane);
    __syncthreads();
    if (tid == 0) *flag = (cnt >= 64) ? 1 : 0;
}

// ---------------- widen inputs to f32 in workspace (23 plain entries) ----------------
struct WD { const void* src; float* dst; int n; };
struct WDT { WD e[23]; };
__global__ __launch_bounds__(256) void widen_all_kernel(WDT tab, const int* __restrict__ flag) {
    WD d = tab.e[blockIdx.y];
    const int f = *flag;
    const int stride = gridDim.x * 256;
    int i = blockIdx.x * 256 + threadIdx.x;
    if (f) {
        const float* s = (const float*)d.src;
        for (; i < d.n; i += stride) d.dst[i] = s[i];
    } else {
        const unsigned short* s = (const unsigned short*)d.src;
        for (; i < d.n; i += stride) d.dst[i] = us2f(s[i]);
    }
}

// ---------------- widen + column-permute the xproj weights -----------------------
__global__ __launch_bounds__(256) void widen_permute_xproj_kernel(
    const void* __restrict__ src, float* __restrict__ dst, const int* __restrict__ flag)
{
    int i = blockIdx.x * 256 + threadIdx.x;   // 512*288 = 147456
    if (i >= 147456) return;
    int k = i / 288, c = i - k * 288;
    int s;
    if (c < 32) s = c;
    else if (c < 160) { int q = c - 32;  s = 32  + (q >> 2) + 32 * (q & 3); }
    else             { int q = c - 160; s = 160 + (q >> 2) + 32 * (q & 3); }
    int si = k * 288 + s;
    float v = (*flag) ? ((const float*)src)[si] : us2f(((const unsigned short*)src)[si]);
    dst[i] = v;
}

// ---------------- bf16-MFMA GEMM (f32 in/out, bf16 matrix cores) ------------------
__global__ __launch_bounds__(256) void gemm_mfma_kernel(
    const float* __restrict__ A, int lda, long long sA,
    const float* __restrict__ W, int N,
    const float* __restrict__ bias,
    float* __restrict__ C, int ldc, long long sC,
    int M, int K, int act)
{
    A += (size_t)blockIdx.z * sA;
    C += (size_t)blockIdx.z * sC;
    __shared__ __align__(16) unsigned short As[64][40];   // [m][k] bf16
    __shared__ __align__(16) unsigned short Bs[64][40];   // [n][k] bf16 (transposed)
    const int tid = threadIdx.x;
    const int wave = tid >> 6, lane = tid & 63;
    const int bm = blockIdx.x * 64, bn = blockIdx.y * 64;
    const int col = lane & 15, quad = lane >> 4;

    f32x4 acc[4] = {{0.f,0.f,0.f,0.f},{0.f,0.f,0.f,0.f},{0.f,0.f,0.f,0.f},{0.f,0.f,0.f,0.f}};

    const int ar = tid >> 2, ak = (tid & 3) << 3;
    const int kr = tid >> 3, nb = (tid & 7) << 3;

    for (int kt = 0; kt < K; kt += 32) {
        float va[8];
        int gm = bm + ar;
        if (gm < M) {
            const float* ap = A + (size_t)gm * lda + kt + ak;
            float4 v0 = *(const float4*)ap;
            float4 v1 = *(const float4*)(ap + 4);
            va[0]=v0.x; va[1]=v0.y; va[2]=v0.z; va[3]=v0.w;
            va[4]=v1.x; va[5]=v1.y; va[6]=v1.z; va[7]=v1.w;
        } else {
#pragma unroll
            for (int j = 0; j < 8; ++j) va[j] = 0.f;
        }
        float vb[8];
        int gn0 = bn + nb;
        const float* wp = W + (size_t)(kt + kr) * N + gn0;
        if (gn0 + 7 < N) {
            float4 w0 = *(const float4*)wp;
            float4 w1 = *(const float4*)(wp + 4);
            vb[0]=w0.x; vb[1]=w0.y; vb[2]=w0.z; vb[3]=w0.w;
            vb[4]=w1.x; vb[5]=w1.y; vb[6]=w1.z; vb[7]=w1.w;
        } else {
#pragma unroll
            for (int j = 0; j < 8; ++j) vb[j] = (gn0 + j < N) ? wp[j] : 0.f;
        }
        __syncthreads();
        bfx8 apk;
#pragma unroll
        for (int j = 0; j < 8; ++j) apk[j] = (short)f2bf(va[j]);
        *(bfx8*)&As[ar][ak] = apk;
#pragma unroll
        for (int j = 0; j < 8; ++j) Bs[nb + j][kr] = f2bf(vb[j]);
        __syncthreads();
        bfx8 af = *(const bfx8*)&As[wave * 16 + col][quad << 3];
#pragma unroll
        for (int ct = 0; ct < 4; ++ct) {
            bfx8 bf = *(const bfx8*)&Bs[ct * 16 + col][quad << 3];
            acc[ct] = __builtin_amdgcn_mfma_f32_16x16x32_bf16(af, bf, acc[ct], 0, 0, 0);
        }
    }
#pragma unroll
    for (int ct = 0; ct < 4; ++ct) {
        int gn = bn + ct * 16 + col;
        if (gn >= N) continue;
        float bv = bias ? bias[gn] : 0.f;
#pragma unroll
        for (int r = 0; r < 4; ++r) {
            int gm = bm + wave * 16 + quad * 4 + r;
            if (gm < M) {
                float v = acc[ct][r] + bv;
                if (act == 1) v = fmaxf(v, 0.f);
                C[(size_t)gm * ldc + gn] = v;
            }
        }
    }
}

// ---------------- causal depthwise conv (K=4) + silu, batched 2 dirs ----------------
__global__ __launch_bounds__(256) void conv_silu_kernel(
    const float* __restrict__ xzbase, int ld, long long bstride,
    const float* __restrict__ conv_w, const float* __restrict__ conv_b,
    float* __restrict__ xs, int T, int rev_mode)
{
    int idx = blockIdx.x * 256 + threadIdx.x;
    if (idx >= 2 * T * DI) return;
    int half = idx / (T * DI);
    int rem = idx - half * T * DI;
    int t = rem >> 9, d = rem & 511;
    const float* xzp = xzbase + (rev_mode ? 0 : (size_t)half * bstride);
    int rev = rev_mode ? half : 0;
    float acc = conv_b[d];
#pragma unroll
    for (int k = 0; k < 4; ++k) {
        int tt = t - 3 + k;
        if (tt >= 0) {
            int g = rev ? (T - 1 - tt) : tt;
            acc += conv_w[d * 4 + k] * xzp[(size_t)g * ld + d];
        }
    }
    xs[idx] = acc * sigm(acc);
}

// ---------------- dt projection (K=32) + softplus ----------------
__global__ __launch_bounds__(256) void dt_kernel(
    const float* __restrict__ xdbl, const float* __restrict__ dt_w,
    const float* __restrict__ dt_b, float* __restrict__ dtout, int T)
{
    int idx = blockIdx.x * 256 + threadIdx.x;
    if (idx >= 2 * T * DI) return;
    int half = idx / (T * DI);
    int rem = idx - half * T * DI;
    int t = rem >> 9, j = rem & 511;
    const float* a = xdbl + (size_t)half * T * XPN + (size_t)t * XPN;
    float acc = dt_b[j];
#pragma unroll
    for (int k = 0; k < 32; ++k) acc += a[k] * dt_w[k * DI + j];
    dtout[idx] = (acc > 20.f) ? acc : log1pf(__expf(acc));
}

// ---------------- gz precompute: gz[half][t][d] = silu(z[flip(t)][d]) ----------------
__global__ __launch_bounds__(256) void gz_kernel(
    const float* __restrict__ xz, float* __restrict__ gz, int T)
{
    int idx = blockIdx.x * 256 + threadIdx.x;
    if (idx >= 2 * T * DI) return;
    int half = idx / (T * DI);
    int rem = idx - half * T * DI;
    int t = rem >> 9, d = rem & 511;
    int tg = half ? (T - 1 - t) : t;
    float z = xz[(size_t)tg * 1024 + 512 + d];
    gz[idx] = z * sigm(z);
}

// ---------------- chunked scan pass 1 (2 d's/wave, 4 waves/block, unroll x2) --------
__global__ __launch_bounds__(256) void scan_part1_kernel(
    const float* __restrict__ dt, const float* __restrict__ xdbl,
    const float* __restrict__ xs, const float* __restrict__ A_log,
    float* __restrict__ P, float* __restrict__ H, int T, int NC, int LC)
{
    int b = blockIdx.x * 4 + (threadIdx.x >> 6);
    int c = b % NC;
    int dp = b / NC;
    int hd0 = dp * 2;
    int half = hd0 >> 9;
    int lane = threadIdx.x & 63;
    int g = lane >> 5, l = lane & 31;
    int hd = hd0 + g;
    int d = hd & 511;
    const float a0 = -__expf(A_log[d * NS + l])      * L2E;
    const float a1 = -__expf(A_log[d * NS + 32 + l]) * L2E;
    const float a2 = -__expf(A_log[d * NS + 64 + l]) * L2E;
    const float a3 = -__expf(A_log[d * NS + 96 + l]) * L2E;
    int t0 = c * LC, t1 = min(T, t0 + LC);
    const float* dtp = dt + (size_t)half * T * DI + (size_t)t0 * DI + d;
    const float* xsp = xs + (size_t)half * T * DI + (size_t)t0 * DI + d;
    const float* row = xdbl + (size_t)half * T * XPN + (size_t)t0 * XPN + 32 + 4 * l;
    float P0 = 1.f, P1 = 1.f, P2 = 1.f, P3 = 1.f;
    float h0 = 0.f, h1 = 0.f, h2 = 0.f, h3 = 0.f;
    int t = t0;
    for (; t + 2 <= t1; t += 2) {
        float dva = dtp[0],  xva = xsp[0];
        float dvb = dtp[DI], xvb = xsp[DI];
        float4 Ba = *(const float4*)row;
        float4 Bb = *(const float4*)(row + XPN);
        float e0a = fexp2(dva * a0), e1a = fexp2(dva * a1);
        float e2a = fexp2(dva * a2), e3a = fexp2(dva * a3);
        float e0b = fexp2(dvb * a0), e1b = fexp2(dvb * a1);
        float e2b = fexp2(dvb * a2), e3b = fexp2(dvb * a3);
        float ua = dva * xva, ub = dvb * xvb;
        h0 = h0 * e0a + ua * Ba.x;  h1 = h1 * e1a + ua * Ba.y;
        h2 = h2 * e2a + ua * Ba.z;  h3 = h3 * e3a + ua * Ba.w;
        h0 = h0 * e0b + ub * Bb.x;  h1 = h1 * e1b + ub * Bb.y;
        h2 = h2 * e2b + ub * Bb.z;  h3 = h3 * e3b + ub * Bb.w;
        P0 *= e0a * e0b; P1 *= e1a * e1b; P2 *= e2a * e2b; P3 *= e3a * e3b;
        dtp += 2 * DI; xsp += 2 * DI; row += 2 * XPN;
    }
    for (; t < t1; ++t) {
        float dv = *dtp, xv = *xsp;
        float4 Bv = *(const float4*)row;
        float e0 = fexp2(dv * a0), e1 = fexp2(dv * a1);
        float e2 = fexp2(dv * a2), e3 = fexp2(dv * a3);
        float u = dv * xv;
        h0 = h0 * e0 + u * Bv.x;  h1 = h1 * e1 + u * Bv.y;
        h2 = h2 * e2 + u * Bv.z;  h3 = h3 * e3 + u * Bv.w;
        P0 *= e0; P1 *= e1; P2 *= e2; P3 *= e3;
        dtp += DI; xsp += DI; row += XPN;
    }
    size_t base = ((size_t)hd * NC + c) * 128 + l;
    P[base] = P0; P[base + 32] = P1; P[base + 64] = P2; P[base + 96] = P3;
    H[base] = h0; H[base + 32] = h1; H[base + 64] = h2; H[base + 96] = h3;
}

// ---------------- chunked scan pass 2: serial combine across chunks ----------------
__global__ __launch_bounds__(128) void scan_combine_kernel(
    float* __restrict__ P, const float* __restrict__ H,
    float* __restrict__ Hfinal, int NC)
{
    int hd = blockIdx.x;
    int n = threadIdx.x;
    size_t base = (size_t)hd * NC * 128 + n;
    float h = 0.f;
    for (int c = 0; c < NC; ++c) {
        size_t off = base + (size_t)c * 128;
        float p = P[off];
        float hh = H[off];
        P[off] = h;                // h_start for chunk c (exclusive prefix)
        h = p * h + hh;
    }
    if (Hfinal) Hfinal[(size_t)hd * 128 + n] = h;
}

// ---------------- chunked scan pass 3: replay + emit gated y (unroll x2, gz) --------
__global__ __launch_bounds__(256) void scan_emit_kernel(
    const float* __restrict__ dt, const float* __restrict__ xdbl,
    const float* __restrict__ xs, const float* __restrict__ gz,
    const float* __restrict__ A_log, const float* __restrict__ Hstart,
    const float* __restrict__ Dp,
    float* __restrict__ y, int T, int NC, int LC)
{
    int b = blockIdx.x * 4 + (threadIdx.x >> 6);
    int c = b % NC;
    int dp = b / NC;
    int hd0 = dp * 2;
    int half = hd0 >> 9;
    int lane = threadIdx.x & 63;
    int g = lane >> 5, l = lane & 31;
    int hd = hd0 + g;
    int d = hd & 511;
    const float a0 = -__expf(A_log[d * NS + l])      * L2E;
    const float a1 = -__expf(A_log[d * NS + 32 + l]) * L2E;
    const float a2 = -__expf(A_log[d * NS + 64 + l]) * L2E;
    const float a3 = -__expf(A_log[d * NS + 96 + l]) * L2E;
    const float Dv = Dp[d];
    size_t base = ((size_t)hd * NC + c) * 128 + l;
    float h0 = Hstart[base];
    float h1 = Hstart[base + 32];
    float h2 = Hstart[base + 64];
    float h3 = Hstart[base + 96];
    int t0 = c * LC, t1 = min(T, t0 + LC);
    size_t lin = (size_t)half * T * DI + (size_t)t0 * DI + d;
    const float* dtp = dt + lin;
    const float* xsp = xs + lin;
    const float* gzp = gz + lin;
    float* yp = y + lin;
    const float* row = xdbl + (size_t)half * T * XPN + (size_t)t0 * XPN + 4 * l;
    int t = t0;
    for (; t + 2 <= t1; t += 2) {
        float dva = dtp[0],  xva = xsp[0];
        float dvb = dtp[DI], xvb = xsp[DI];
        float4 Ba = *(const float4*)(row + 32);
        float4 Ca = *(const float4*)(row + 160);
        float4 Bb = *(const float4*)(row + XPN + 32);
        float4 Cb = *(const float4*)(row + XPN + 160);
        float e0a = fexp2(dva * a0), e1a = fexp2(dva * a1);
        float e2a = fexp2(dva * a2), e3a = fexp2(dva * a3);
        float e0b = fexp2(dvb * a0), e1b = fexp2(dvb * a1);
        float e2b = fexp2(dvb * a2), e3b = fexp2(dvb * a3);
        float ua = dva * xva, ub = dvb * xvb;
        h0 = h0 * e0a + ua * Ba.x;  h1 = h1 * e1a + ua * Ba.y;
        h2 = h2 * e2a + ua * Ba.z;  h3 = h3 * e3a + ua * Ba.w;
        float pa = h0 * Ca.x + h1 * Ca.y + h2 * Ca.z + h3 * Ca.w;
        h0 = h0 * e0b + ub * Bb.x;  h1 = h1 * e1b + ub * Bb.y;
        h2 = h2 * e2b + ub * Bb.z;  h3 = h3 * e3b + ub * Bb.w;
        float pb = h0 * Cb.x + h1 * Cb.y + h2 * Cb.z + h3 * Cb.w;
        pa += __shfl_xor(pa, 1, 64);  pb += __shfl_xor(pb, 1, 64);
        pa += __shfl_xor(pa, 2, 64);  pb += __shfl_xor(pb, 2, 64);
        pa += __shfl_xor(pa, 4, 64);  pb += __shfl_xor(pb, 4, 64);
        pa += __shfl_xor(pa, 8, 64);  pb += __shfl_xor(pb, 8, 64);
        pa += __shfl_xor(pa, 16, 64); pb += __shfl_xor(pb, 16, 64);
        if (l == 0) {
            yp[0]  = (pa + xva * Dv) * gzp[0];
            yp[DI] = (pb + xvb * Dv) * gzp[DI];
        }
        dtp += 2 * DI; xsp += 2 * DI; row += 2 * XPN; yp += 2 * DI; gzp += 2 * DI;
    }
    for (; t < t1; ++t) {
        float dv = *dtp, xv = *xsp;
        float4 Bv = *(const float4*)(row + 32);
        float4 Cv = *(const float4*)(row + 160);
        float e0 = fexp2(dv * a0), e1 = fexp2(dv * a1);
        float e2 = fexp2(dv * a2), e3 = fexp2(dv * a3);
        float u = dv * xv;
        h0 = h0 * e0 + u * Bv.x;  h1 = h1 * e1 + u * Bv.y;
        h2 = h2 * e2 + u * Bv.z;  h3 = h3 * e3 + u * Bv.w;
        float p = h0 * Cv.x + h1 * Cv.y + h2 * Cv.z + h3 * Cv.w;
        p += __shfl_xor(p, 1, 64);
        p += __shfl_xor(p, 2, 64);
        p += __shfl_xor(p, 4, 64);
        p += __shfl_xor(p, 8, 64);
        p += __shfl_xor(p, 16, 64);
        if (l == 0) *yp = (p + xv * Dv) * (*gzp);
        dtp += DI; xsp += DI; row += XPN; yp += DI; gzp += DI;
    }
}

// ---------------- cross: last-step readout (permuted C layout) ----------------
__global__ __launch_bounds__(64) void cross_readout_kernel(
    const float* __restrict__ Hfinal, const float* __restrict__ xdbl,
    const float* __restrict__ xs, const float* __restrict__ xz,
    const float* __restrict__ Dp, float* __restrict__ ylast, int T)
{
    int hd = blockIdx.x;
    int half = hd >> 9, d = hd & 511;
    int lane = threadIdx.x;
    xdbl += (size_t)half * T * XPN;
    xs   += (size_t)half * T * DI;
    xz   += (size_t)half * T * 1024;
    float h0 = Hfinal[(size_t)hd * 128 + lane];          // state n = lane
    float h1 = Hfinal[(size_t)hd * 128 + 64 + lane];     // state n = 64+lane
    const float* xl = xdbl + (size_t)(T - 1) * XPN;
    int lb = lane & 31, j = lane >> 5;
    float C0 = xl[160 + 4 * lb + j];        // permuted col of state n=lane
    float C1 = xl[160 + 4 * lb + 2 + j];    // permuted col of state n=64+lane
    float p = h0 * C0 + h1 * C1;
#pragma unroll
    for (int off = 32; off > 0; off >>= 1) p += __shfl_down(p, off, 64);
    if (lane == 0) {
        float xlast = xs[(size_t)(T - 1) * DI + d];
        float zl = xz[(size_t)(T - 1) * 1024 + 512 + d];
        ylast[half * DI + d] = (p + xlast * Dp[d]) * (zl * sigm(zl));
    }
}

// ---------------- row softmax + scatter into both cross sequences ----------------
__global__ __launch_bounds__(256) void softmax_scatter_kernel(
    const float* __restrict__ yo, float* __restrict__ seq, int T)
{
    __shared__ float sm[4];
    const int t = blockIdx.x, half = blockIdx.y, tid = threadIdx.x;
    const float* row = yo + (size_t)half * T * DI + (size_t)t * DI;
    float v0 = row[tid], v1 = row[tid + 256];
    float m = fmaxf(v0, v1);
#pragma unroll
    for (int o = 32; o > 0; o >>= 1) m = fmaxf(m, __shfl_xor(m, o, 64));
    if ((tid & 63) == 0) sm[tid >> 6] = m;
    __syncthreads();
    m = fmaxf(fmaxf(sm[0], sm[1]), fmaxf(sm[2], sm[3]));
    __syncthreads();
    float e0 = __expf(v0 - m), e1 = __expf(v1 - m);
    float s = e0 + e1;
#pragma unroll
    for (int o = 32; o > 0; o >>= 1) s += __shfl_xor(s, o, 64);
    if ((tid & 63) == 0) sm[tid >> 6] = s;
    __syncthreads();
    s = sm[0] + sm[1] + sm[2] + sm[3];
    float inv = 1.f / s;
    e0 *= inv; e1 *= inv;
    float* seq_fi = seq;
    float* seq_if = seq + (size_t)TC * 1024;
    if (half == 0) {
        float* d1 = seq_fi + (size_t)t * 1024;
        float* d2 = seq_if + (size_t)t * 1024 + 512;
        d1[tid] = e0; d1[tid + 256] = e1;
        d2[tid] = e0; d2[tid + 256] = e1;
    } else {
        int tg = T - 1 - t;
        float* d1 = seq_fi + (size_t)tg * 1024 + 512;
        float* d2 = seq_if + (size_t)tg * 1024;
        d1[tid] = e0; d1[tid + 256] = e1;
        d2[tid] = e0; d2[tid + 256] = e1;
    }
}

// ---------------- cls-token rows of the two sequences ----------------
__global__ __launch_bounds__(256) void cls_rows_kernel(
    const float* __restrict__ cls1, const float* __restrict__ cls2,
    float* __restrict__ seq)
{
    int i = blockIdx.x * 256 + threadIdx.x;   // 0..2047
    if (i < 1024)
        seq[(size_t)(TC - 1) * 1024 + i] = cls1[i];
    else
        seq[(size_t)TC * 1024 + (size_t)(TC - 1) * 1024 + (i - 1024)] = cls2[i - 1024];
}

// ---------------- vec [512] @ out_w [512,512] -> [512] ----------------
__global__ __launch_bounds__(256) void vecmat_kernel(
    const float* __restrict__ ylast, const float* __restrict__ Wout,
    float* __restrict__ olast)
{
    int half = blockIdx.y;
    int j = blockIdx.x * 256 + threadIdx.x;
    const float* v = ylast + half * DI;
    float acc = 0.f;
    for (int k = 0; k < DI; ++k) acc += v[k] * Wout[k * DI + j];
    olast[half * DI + j] = acc;
}

// ---------------- final classifier -> f32 [2] ----------------
__global__ __launch_bounds__(256) void final_kernel(
    const float* __restrict__ ol, const float* __restrict__ cw,
    const float* __restrict__ cb, float* __restrict__ out)
{
    __shared__ float s0[4], s1[4];
    int tid = threadIdx.x;
    float a0 = 0.f, a1 = 0.f;
    for (int j = tid; j < 1024; j += 256) {
        float v = ol[j];
        a0 += v * cw[2 * j];
        a1 += v * cw[2 * j + 1];
    }
#pragma unroll
    for (int o = 32; o > 0; o >>= 1) { a0 += __shfl_xor(a0, o, 64); a1 += __shfl_xor(a1, o, 64); }
    if ((tid & 63) == 0) { s0[tid >> 6] = a0; s1[tid >> 6] = a1; }
    __syncthreads();
    if (tid == 0) {
        out[0] = s0[0] + s0[1] + s0[2] + s0[3] + cb[0];
        out[1] = s1[0] + s1[1] + s1[2] + s1[3] + cb[1];
    }
}

extern "C" void kernel_launch(void* const* d_in, const int* in_sizes, int n_in,
                              void* d_out, int out_size, void* d_ws, size_t ws_size,
                              hipStream_t stream)
{
    float* out = (float*)d_out;
    float* ws = (float*)d_ws;

    // ---- input-order resolution via in_sizes (dict vs signature order) ----
    static const int sig_map[25] = {0,1,2,3,4,23,24,5,6,7,8,9,10,11,12,13,
                                    14,15,16,17,18,19,20,21,22};
    int idx[25];
    bool dict_order = (n_in >= 7 && in_sizes[6] == 2);
    for (int i = 0; i < 25; ++i) idx[i] = dict_order ? i : sig_map[i];

    // ---- aliased workspace layout (f32 elements) ----
    const size_t A0 = 0;         // x(f32) -> dt_simple -> yo -> XSC          (2,098,176)
    const size_t B0 = 2098176;   // f -> XDC                                  (1,180,224)
    const size_t C0 = 3278400;   // XZS / XZC (XZC spans ..7,474,752)         (2,097,152)
    const size_t D0 = 5375552;   // XS                                        (2,097,152)
    const size_t E0 = 7472704;   // XDBL                                      (1,179,648)
    const size_t F0 = 8652352;   // y / YS                                    (2,097,152)
    const size_t G0 = 10749504;  // P_S | H_S(->gz)  -> SEQ                   (4,196,352)
    const size_t YL0 = 14945856; // 1024
    const size_t OL0 = 14946880; // 1024
    const size_t DT_S = A0;
    const size_t P_S  = G0;
    const size_t H_S  = G0 + 2097152;   // H for part1/combine; reused as gz for emit
    const size_t DT_C = 7474752;
    const size_t P_C  = 9572928;
    const size_t H_C  = 11801152;
    const size_t HFIN = 14029376;
    size_t o = 14947904;
    const size_t P_FEATW = o; o += 524288;
    const size_t P_FEATB = o; o += 512;
    const size_t P_CLS1  = o; o += 1024;
    const size_t P_CLS2  = o; o += 1024;
    const size_t P_CLSW  = o; o += 2048;
    const size_t P_CLSB  = o; o += 4;
    const size_t P_MINW  = o; o += 524288;
    const size_t P_MCW   = o; o += 2048;
    const size_t P_MCB   = o; o += 512;
    const size_t P_MXP   = o; o += 147456;
    const size_t P_MDTW  = o; o += 16384;
    const size_t P_MDTB  = o; o += 512;
    const size_t P_MAL   = o; o += 65536;
    const size_t P_MD    = o; o += 512;
    const size_t P_MOW   = o; o += 262144;
    const size_t P_CINW  = o; o += 1048576;
    const size_t P_CCW   = o; o += 2048;
    const size_t P_CCB   = o; o += 512;
    const size_t P_CXP   = o; o += 147456;
    const size_t P_CDTW  = o; o += 16384;
    const size_t P_CDTB  = o; o += 512;
    const size_t P_CAL   = o; o += 65536;
    const size_t P_CD    = o; o += 512;
    const size_t P_COW   = o; o += 262144;
    const size_t OFF_FLAG = o;               // 1 int

    int* flagp = (int*)(ws + OFF_FLAG);

    // 0) detect input dtype
    detect_kernel<<<1, 256, 0, stream>>>((const unsigned short*)d_in[idx[0]], flagp);

    // 1) widen inputs (23 plain + 2 permuted xproj)
    WDT tab;
    const int lg[23]  = {0,1,2,3,4,5,6,7,8,9,11,12,13,14,15,16,17,18,20,21,22,23,24};
    const int nsl[25] = {2097152, 524288, 512, 1024, 1024, 2048, 2,
                         524288, 2048, 512, 147456, 16384, 512, 65536, 512, 262144,
                         1048576, 2048, 512, 147456, 16384, 512, 65536, 512, 262144};
    float* dstl[25] = {
        ws + A0, ws + P_FEATW, ws + P_FEATB, ws + P_CLS1, ws + P_CLS2,
        ws + P_CLSW, ws + P_CLSB,
        ws + P_MINW, ws + P_MCW, ws + P_MCB, nullptr, ws + P_MDTW, ws + P_MDTB,
        ws + P_MAL, ws + P_MD, ws + P_MOW,
        ws + P_CINW, ws + P_CCW, ws + P_CCB, nullptr, ws + P_CDTW, ws + P_CDTB,
        ws + P_CAL, ws + P_CD, ws + P_COW};
    for (int i = 0; i < 23; ++i) {
        int s = lg[i];
        tab.e[i].src = d_in[idx[s]];
        tab.e[i].dst = dstl[s];
        tab.e[i].n = nsl[s];
    }
    widen_all_kernel<<<dim3(128, 23), 256, 0, stream>>>(tab, flagp);
    widen_permute_xproj_kernel<<<576, 256, 0, stream>>>(d_in[idx[10]], ws + P_MXP, flagp);
    widen_permute_xproj_kernel<<<576, 256, 0, stream>>>(d_in[idx[19]], ws + P_CXP, flagp);

    // 2) f = relu(x @ feat_w + feat_b)        A -> B
    gemm_mfma_kernel<<<dim3(32, 8, 1), 256, 0, stream>>>(ws + A0, 1024, 0, ws + P_FEATW, 512,
                                                         ws + P_FEATB, ws + B0, 512, 0,
                                                         2048, 1024, 1);
    // 3) xz = f @ m_in_w                      B -> C
    gemm_mfma_kernel<<<dim3(32, 16, 1), 256, 0, stream>>>(ws + B0, 512, 0, ws + P_MINW, 1024,
                                                          nullptr, ws + C0, 1024, 0,
                                                          2048, 512, 0);
    // 4) conv+silu, both directions           C -> D
    conv_silu_kernel<<<8192, 256, 0, stream>>>(ws + C0, 1024, 0, ws + P_MCW, ws + P_MCB,
                                               ws + D0, 2048, 1);
    // 5) x_dbl = xs @ m_xproj_w (permuted)    D -> E
    gemm_mfma_kernel<<<dim3(32, 5, 2), 256, 0, stream>>>(ws + D0, 512, 2048LL * 512, ws + P_MXP,
                                                         288, nullptr, ws + E0, 288, 2048LL * 288,
                                                         2048, 512, 0);
    // 5b) dt = softplus(x_dbl[:, :32] @ dt_w + dt_b)   E -> DT_S (A)
    dt_kernel<<<8192, 256, 0, stream>>>(ws + E0, ws + P_MDTW, ws + P_MDTB, ws + DT_S, 2048);
    // 6) chunked scan: T=2048, 16 chunks x 128
    scan_part1_kernel<<<2048, 256, 0, stream>>>(ws + DT_S, ws + E0, ws + D0, ws + P_MAL,
                                                ws + P_S, ws + H_S, 2048, 16, 128);
    scan_combine_kernel<<<1024, 128, 0, stream>>>(ws + P_S, ws + H_S, nullptr, 16);
    // 6a) gz = silu(z[flip])                  C -> H_S (H dead after combine)
    gz_kernel<<<8192, 256, 0, stream>>>(ws + C0, ws + H_S, 2048);
    // 6b) emit with fused gating via gz
    scan_emit_kernel<<<2048, 256, 0, stream>>>(ws + DT_S, ws + E0, ws + D0, ws + H_S,
                                               ws + P_MAL, ws + P_S, ws + P_MD,
                                               ws + F0, 2048, 16, 128);
    // 7) yo = y @ m_out_w                     F -> A (yo)
    gemm_mfma_kernel<<<dim3(32, 8, 2), 256, 0, stream>>>(ws + F0, 512, 2048LL * 512, ws + P_MOW,
                                                         512, nullptr, ws + A0, 512, 2048LL * 512,
                                                         2048, 512, 0);
    // 8) cls-token rows into SEQ              P -> G
    cls_rows_kernel<<<8, 256, 0, stream>>>(ws + P_CLS1, ws + P_CLS2, ws + G0);
    // 9) softmax + scatter                    A -> G
    softmax_scatter_kernel<<<dim3(2048, 2), 256, 0, stream>>>(ws + A0, ws + G0, 2048);
    // 10) cross in-proj                       G -> C (XZC spans C,D,+head of E)
    gemm_mfma_kernel<<<dim3(33, 16, 2), 256, 0, stream>>>(ws + G0, 1024, 2049LL * 1024, ws + P_CINW,
                                                          1024, nullptr, ws + C0, 1024,
                                                          2049LL * 1024, 2049, 1024, 0);
    // 11) cross conv+silu                     C -> A (XSC)
    conv_silu_kernel<<<8196, 256, 0, stream>>>(ws + C0, 1024, 2049LL * 1024, ws + P_CCW,
                                               ws + P_CCB, ws + A0, 2049, 0);
    // 12) cross x_dbl (permuted)              A -> B (XDC)
    gemm_mfma_kernel<<<dim3(33, 5, 2), 256, 0, stream>>>(ws + A0, 512, 2049LL * 512, ws + P_CXP,
                                                         288, nullptr, ws + B0, 288, 2049LL * 288,
                                                         2049, 512, 0);
    // 12b) cross dt                           B -> DT_C
    dt_kernel<<<8196, 256, 0, stream>>>(ws + B0, ws + P_CDTW, ws + P_CDTB, ws + DT_C, 2049);
    // 13) cross chunked scan: T=2049, 17 chunks x 128
    scan_part1_kernel<<<2176, 256, 0, stream>>>(ws + DT_C, ws + B0, ws + A0, ws + P_CAL,
                                                ws + P_C, ws + H_C, 2049, 17, 128);
    scan_combine_kernel<<<1024, 128, 0, stream>>>(ws + P_C, ws + H_C, ws + HFIN, 17);
    cross_readout_kernel<<<1024, 64, 0, stream>>>(ws + HFIN, ws + B0, ws + A0, ws + C0,
                                                  ws + P_CD, ws + YL0, 2049);
    // 14) out-projection of last rows         YL -> OL
    vecmat_kernel<<<dim3(2, 2), 256, 0, stream>>>(ws + YL0, ws + P_COW, ws + OL0);
    // 15) classifier                          OL -> out (f32)
    final_kernel<<<1, 256, 0, stream>>>(ws + OL0, ws + P_CLSW, ws + P_CLSB, out);
}